// Round 13
// baseline (508.645 us; speedup 1.0000x reference)
//
#include <hip/hip_runtime.h>
#include <math.h>

// CTC loss (per-step-normalized fwd/bwd), B=128, C=512, T=512, S=128, L=257.
// Round-13: MEASUREMENT ROUND. Real pipeline = round-10 verbatim (79.5us PASS).
// Added 4 diagnostic kernels (dummy-ws writes only), each looped to exceed the
// ~80us harness-fill floor so they appear in rocprof top-5 by name:
//   ctc_diagL: recursion+reduce+LOADS (no stores), x3   -> load cost
//   ctc_diagS: recursion+reduce+pack+STORES (no loads), x4 -> store cost
//   ctc_diagM: recursion+reduce only, x6                -> math/issue floor
//   ctc_diagC: combine clone (laundered ptrs), x5       -> combine cost
// Decomposition: load=L/3-M/6, store=S/4-M/6, floor=M/6, combine=C/5.
// asm-volatile sinks defeat DCE (guide rule #17).

#define BB 128
#define CC 512
#define TT 512
#define SS 128
#define LL 257
#define LPADH 260   // bf16 (ushort) elements per row

typedef unsigned int  uint;
typedef unsigned short ushort;

// ---- fp32 DPP helpers (gfx9 controls; validated on gfx950 rounds 3-11) ----
template<int CTRL>
__device__ __forceinline__ float dpp0_f32(float x){
    int v = __builtin_bit_cast(int, x);
    int r = __builtin_amdgcn_update_dpp(0, v, CTRL, 0xF, 0xF, true);
    return __builtin_bit_cast(float, r);
}
__device__ __forceinline__ float shfl_up1_f32(float x){ return dpp0_f32<0x138>(x); }
__device__ __forceinline__ float red8f(float x){
    x += dpp0_f32<0x111>(x);
    x += dpp0_f32<0x112>(x);
    x += dpp0_f32<0x114>(x);
    return x;
}
__device__ __forceinline__ float tail3f(float x){
    x += dpp0_f32<0x118>(x);
    x += dpp0_f32<0x142>(x);
    x += dpp0_f32<0x143>(x);
    return x;
}
__device__ __forceinline__ float full64f(float x){ return tail3f(red8f(x)); }
__device__ __forceinline__ float readlane63_f32(float x){
    int v = __builtin_bit_cast(int, x);
    return __builtin_bit_cast(float, __builtin_amdgcn_readlane(v, 63));
}
__device__ __forceinline__ float pow2if(int e){
    return __builtin_bit_cast(float, (127 + e) << 23);
}
__device__ __forceinline__ uint pk_bf16(float lo, float hi){
    return (__builtin_bit_cast(uint, hi) & 0xFFFF0000u)
         | (__builtin_bit_cast(uint, lo) >> 16);
}
__device__ __forceinline__ float up_lo(uint u){ return __builtin_bit_cast(float, u << 16); }
__device__ __forceinline__ float up_hi(uint u){ return __builtin_bit_cast(float, u & 0xFFFF0000u); }
__device__ __forceinline__ float up_us(ushort u){ return __builtin_bit_cast(float, ((uint)u) << 16); }
template<int CTRL>
__device__ __forceinline__ double dpp0_f64(double x){
    int2 v = __builtin_bit_cast(int2, x);
    int2 r;
    r.x = __builtin_amdgcn_update_dpp(0, v.x, CTRL, 0xF, 0xF, true);
    r.y = __builtin_amdgcn_update_dpp(0, v.y, CTRL, 0xF, 0xF, true);
    return __builtin_bit_cast(double, r);
}
__device__ __forceinline__ double full64d(double x){
    x += dpp0_f64<0x111>(x); x += dpp0_f64<0x112>(x); x += dpp0_f64<0x114>(x);
    x += dpp0_f64<0x118>(x); x += dpp0_f64<0x142>(x); x += dpp0_f64<0x143>(x);
    return x;
}

// =================== REAL row-storing scan (round-10 verbatim) ===================
template<bool REV>
__device__ __forceinline__ void scan_body(
    int b, int l, const float* __restrict__ P, const int* __restrict__ seqg,
    int blank, ushort* __restrict__ W, ushort* __restrict__ W4,
    int* __restrict__ Eb)
{
    const bool is63 = (l == 63);
    const float* Pb = P + (size_t)b * (CC*TT);
    const int* sq = seqg + b*SS;

    int r1, r3; float m1, m3;
    if (!REV) {
        r1 = sq[2*l]; r3 = sq[2*l+1];
        int ip = (l==0) ? 0 : (2*l-1);
        m1 = (l==0) ? 1.f : ((r1 != sq[ip]) ? 1.f : 0.f);
        m3 = (r3 != r1) ? 1.f : 0.f;
    } else {
        r1 = sq[SS-1-2*l]; r3 = sq[SS-2-2*l];
        int ip = (l==0) ? 0 : (SS-2*l);
        m1 = (l==0) ? 1.f : ((r1 != sq[ip]) ? 1.f : 0.f);
        m3 = (r3 != r1) ? 1.f : 0.f;
    }
    const float* pBp = Pb + (size_t)blank*TT;
    const float* p1p = Pb + (size_t)r1*TT;
    const float* p3p = Pb + (size_t)r3*TT;
    ushort* Ww  = W  + (size_t)b*TT*LPADH;
    ushort* W4b = W4 + (size_t)b*TT;
    int* EbB = Eb + b*64;

    const int tm0=(4*l+769)>>1, tm1=(4*l+770)>>1, tm2=(4*l+771)>>1, tm3=(4*l+772)>>1;

    float pbB[8], pb1[8], pb3[8];
    #pragma unroll
    for (int j=0;j<8;++j){
        int pc = REV ? (TT-1-j) : j;
        pbB[j]=pBp[pc]; pb1[j]=p1p[pc]; pb3[j]=p3p[pc];
    }

    float a0=0.f,a1=0.f,a2=0.f,a3=0.f,a4=0.f;
    float scNext = 1.f, Sfull = 0.f;
    const float u0i = (l==0) ? 1.f : 0.f;
    uint sbLo[8], sbHi[8]; float s4f[8];

#define STEP(i, j, FIRSTF, MASKF)                                           \
  {                                                                         \
    float u0,u1,u2,u3,u4;                                                   \
    if (FIRSTF) { u0=u0i; u1=u0i; u2=0.f; u3=0.f; u4=0.f; }                 \
    else {                                                                  \
      float e3u = shfl_up1_f32(a3);                                         \
      u0 = a0 + e3u; u1 = (a1+a0) + m1*e3u; u2 = a2+a1;                     \
      u3 = (a3+a2) + m3*a1; u4 = a4+a3;                                     \
      if (MASKF) {                                                          \
        if ((i) >= tm0) u0 = 0.f;                                           \
        if ((i) >= tm1) u1 = 0.f;                                           \
        if ((i) >= tm2) u2 = 0.f;                                           \
        if ((i) >= tm3) u3 = 0.f;                                           \
      }                                                                     \
    }                                                                       \
    float pB=pbB[j], pq=pb1[j], pr=pb3[j];                                  \
    if ((j)==0) { pB*=scNext; pq*=scNext; pr*=scNext; }                     \
    float n0=u0*pB, n1=u1*pq, n2=u2*pB, n3=u3*pr, n4=u4*pB;                 \
    sbLo[j]=pk_bf16(n0,n1); sbHi[j]=pk_bf16(n2,n3); s4f[j]=n4;              \
    if ((j)==5) {                                                           \
      float part=(n0+n1)+(n2+n3); if (is63) part+=n4;                       \
      Sfull = full64f(part);                                                \
    }                                                                       \
    if ((j)==7) {                                                           \
      float Su = readlane63_f32(Sfull);                                     \
      int ex = (__builtin_bit_cast(int, Su) >> 23) & 0xFF;                  \
      int e = (ex==0) ? 0 : (ex-127);                                       \
      e = e < -120 ? -120 : (e > 120 ? 120 : e);                            \
      scNext = pow2if(-e);                                                  \
      if (REV && l==0 && (i)+1 < TT) EbB[((i)+1)>>3] = e;                   \
    }                                                                       \
    a0=n0; a1=n1; a2=n2; a3=n3; a4=n4;                                      \
    int inx = ((i)+8 < TT) ? (i)+8 : TT-1;                                  \
    int pcn = REV ? (TT-1-inx) : inx;                                       \
    pbB[j]=pBp[pcn]; pb1[j]=p1p[pcn]; pb3[j]=p3p[pcn];                      \
  }

#define GSTORE(i0)                                                          \
  {                                                                         \
    _Pragma("unroll")                                                       \
    for (int j=0;j<8;++j)                                                   \
      *reinterpret_cast<uint2*>(Ww + (size_t)j*LPADH + 4*l)                 \
          = make_uint2(sbLo[j], sbHi[j]);                                   \
    if (is63) {                                                             \
      uint4 pk;                                                             \
      pk.x = pk_bf16(s4f[0], s4f[1]);                                       \
      pk.y = pk_bf16(s4f[2], s4f[3]);                                       \
      pk.z = pk_bf16(s4f[4], s4f[5]);                                       \
      pk.w = pk_bf16(s4f[6], s4f[7]);                                       \
      *reinterpret_cast<uint4*>(W4b + (i0)) = pk;                           \
    }                                                                       \
    Ww += 8*LPADH;                                                          \
  }

    STEP(0,0,true,false)  STEP(1,1,false,false) STEP(2,2,false,false)
    STEP(3,3,false,false) STEP(4,4,false,false) STEP(5,5,false,false)
    STEP(6,6,false,false) STEP(7,7,false,false)
    GSTORE(0)
    for (int i0=8; i0<TT-SS; i0+=8) {
        #pragma unroll
        for (int j=0;j<8;++j) STEP(i0+j, j, false, false)
        GSTORE(i0)
    }
    for (int i0=TT-SS; i0<TT; i0+=8) {
        #pragma unroll
        for (int j=0;j<8;++j) STEP(i0+j, j, false, true)
        GSTORE(i0)
    }
#undef STEP
#undef GSTORE
}

__global__ __launch_bounds__(64, 1)
void ctc_scan(const float* __restrict__ P, const int* __restrict__ seqg,
              const int* __restrict__ blankp, ushort* __restrict__ Wa,
              ushort* __restrict__ Wb, ushort* __restrict__ W4a,
              ushort* __restrict__ W4b, int* __restrict__ Eb)
{
    const int bx = blockIdx.x, l = threadIdx.x;
    const int blank = blankp[0];
    if (bx < BB) scan_body<false>(bx,      l, P, seqg, blank, Wa, W4a, Eb);
    else         scan_body<true >(bx - BB, l, P, seqg, blank, Wb, W4b, Eb);
}

// =================== DIAGNOSTIC scan variants (dummy writes only) ===================
template<bool LOADS, bool STORES, int REPS>
__device__ __forceinline__ void diag_body(
    int bp, int bw, int l, const float* __restrict__ P,
    const int* __restrict__ seqg, int blank,
    ushort* __restrict__ Wdum, ushort* __restrict__ W4dum)
{
    const bool is63 = (l == 63);
    const float* Pb = P + (size_t)bp*(CC*TT);
    const int* sq = seqg + bp*SS;
    const int r1 = sq[2*l], r3 = sq[2*l+1];
    const int ip = (l==0) ? 0 : (2*l-1);
    const float m1 = (l==0) ? 1.f : ((r1 != sq[ip]) ? 1.f : 0.f);
    const float m3 = (r3 != r1) ? 1.f : 0.f;
    const float* pBp = Pb + (size_t)blank*TT;
    const float* p1p = Pb + (size_t)r1*TT;
    const float* p3p = Pb + (size_t)r3*TT;
    const int tm0=(4*l+769)>>1, tm1=(4*l+770)>>1, tm2=(4*l+771)>>1, tm3=(4*l+772)>>1;
    // runtime constants (not foldable) for the no-load variants
    const float cB = 0.437f + (float)blank*1e-7f;
    const float c1 = cB*1.013f, c3 = cB*0.991f;

    float pbB[8], pb1[8], pb3[8];
    float sink0 = 0.f, sink1 = 0.f;

    for (int rep=0; rep<REPS; ++rep) {
        ushort* Ww  = Wdum  + (size_t)bw*TT*LPADH;
        ushort* W4b = W4dum + (size_t)bw*TT;
        float a0=0.f,a1=0.f,a2=0.f,a3=0.f,a4=0.f;
        float scNext = 1.f, Sfull = 0.f;
        const float u0i = (l==0) ? 1.f : 0.f;
        uint sbLo[8], sbHi[8]; float s4f[8];
        if constexpr (LOADS) {
            #pragma unroll
            for (int j=0;j<8;++j){ pbB[j]=pBp[j]; pb1[j]=p1p[j]; pb3[j]=p3p[j]; }
        }

#define DSTEP(i, j, FIRSTF, MASKF)                                          \
  {                                                                         \
    float u0,u1,u2,u3,u4;                                                   \
    if (FIRSTF) { u0=u0i; u1=u0i; u2=0.f; u3=0.f; u4=0.f; }                 \
    else {                                                                  \
      float e3u = shfl_up1_f32(a3);                                         \
      u0 = a0 + e3u; u1 = (a1+a0) + m1*e3u; u2 = a2+a1;                     \
      u3 = (a3+a2) + m3*a1; u4 = a4+a3;                                     \
      if (MASKF) {                                                          \
        if ((i) >= tm0) u0 = 0.f;                                           \
        if ((i) >= tm1) u1 = 0.f;                                           \
        if ((i) >= tm2) u2 = 0.f;                                           \
        if ((i) >= tm3) u3 = 0.f;                                           \
      }                                                                     \
    }                                                                       \
    float pB, pq, pr;                                                       \
    if constexpr (LOADS) { pB=pbB[j]; pq=pb1[j]; pr=pb3[j]; }               \
    else { pB=cB; pq=c1; pr=c3; }                                           \
    if ((j)==0) { pB*=scNext; pq*=scNext; pr*=scNext; }                     \
    float n0=u0*pB, n1=u1*pq, n2=u2*pB, n3=u3*pr, n4=u4*pB;                 \
    if constexpr (STORES) {                                                 \
      sbLo[j]=pk_bf16(n0,n1); sbHi[j]=pk_bf16(n2,n3); s4f[j]=n4;            \
    }                                                                       \
    if ((j)==5) {                                                           \
      float part=(n0+n1)+(n2+n3); if (is63) part+=n4;                       \
      Sfull = full64f(part);                                                \
    }                                                                       \
    if ((j)==7) {                                                           \
      float Su = readlane63_f32(Sfull);                                     \
      int ex = (__builtin_bit_cast(int, Su) >> 23) & 0xFF;                  \
      int e = (ex==0) ? 0 : (ex-127);                                       \
      e = e < -120 ? -120 : (e > 120 ? 120 : e);                            \
      scNext = pow2if(-e);                                                  \
    }                                                                       \
    a0=n0; a1=n1; a2=n2; a3=n3; a4=n4;                                      \
    if constexpr (LOADS) {                                                  \
      int inx = ((i)+8 < TT) ? (i)+8 : TT-1;                                \
      pbB[j]=pBp[inx]; pb1[j]=p1p[inx]; pb3[j]=p3p[inx];                    \
    }                                                                       \
  }

#define DGSTORE(i0)                                                         \
  {                                                                         \
    if constexpr (STORES) {                                                 \
      _Pragma("unroll")                                                     \
      for (int j=0;j<8;++j)                                                 \
        *reinterpret_cast<uint2*>(Ww + (size_t)j*LPADH + 4*l)               \
            = make_uint2(sbLo[j], sbHi[j]);                                 \
      if (is63) {                                                           \
        uint4 pk;                                                           \
        pk.x = pk_bf16(s4f[0], s4f[1]);                                     \
        pk.y = pk_bf16(s4f[2], s4f[3]);                                     \
        pk.z = pk_bf16(s4f[4], s4f[5]);                                     \
        pk.w = pk_bf16(s4f[6], s4f[7]);                                     \
        *reinterpret_cast<uint4*>(W4b + (i0)) = pk;                         \
      }                                                                     \
      Ww += 8*LPADH;                                                        \
    }                                                                       \
  }

        DSTEP(0,0,true,false)  DSTEP(1,1,false,false) DSTEP(2,2,false,false)
        DSTEP(3,3,false,false) DSTEP(4,4,false,false) DSTEP(5,5,false,false)
        DSTEP(6,6,false,false) DSTEP(7,7,false,false)
        DGSTORE(0)
        for (int i0=8; i0<TT-SS; i0+=8) {
            #pragma unroll
            for (int j=0;j<8;++j) DSTEP(i0+j, j, false, false)
            DGSTORE(i0)
        }
        for (int i0=TT-SS; i0<TT; i0+=8) {
            #pragma unroll
            for (int j=0;j<8;++j) DSTEP(i0+j, j, false, true)
            DGSTORE(i0)
        }
#undef DSTEP
#undef DGSTORE
        sink0 += (a0+a1)+(a2+a3)+a4;
        sink1 += scNext;
    }
    asm volatile("" :: "v"(sink0), "v"(sink1));   // defeat DCE (rule #17)
}

__global__ __launch_bounds__(64, 1)
void ctc_diagL(const float* __restrict__ P, const int* __restrict__ seqg,
               const int* __restrict__ blankp, ushort* __restrict__ Wdum,
               ushort* __restrict__ W4dum)
{ diag_body<true,false,3>(blockIdx.x & (BB-1), blockIdx.x, threadIdx.x, P, seqg, blankp[0], Wdum, W4dum); }

__global__ __launch_bounds__(64, 1)
void ctc_diagS(const float* __restrict__ P, const int* __restrict__ seqg,
               const int* __restrict__ blankp, ushort* __restrict__ Wdum,
               ushort* __restrict__ W4dum)
{ diag_body<false,true,4>(blockIdx.x & (BB-1), blockIdx.x, threadIdx.x, P, seqg, blankp[0], Wdum, W4dum); }

__global__ __launch_bounds__(64, 1)
void ctc_diagM(const float* __restrict__ P, const int* __restrict__ seqg,
               const int* __restrict__ blankp, ushort* __restrict__ Wdum,
               ushort* __restrict__ W4dum)
{ diag_body<false,false,6>(blockIdx.x & (BB-1), blockIdx.x, threadIdx.x, P, seqg, blankp[0], Wdum, W4dum); }

// =========================== parallel combine (real) ===========================
__global__ __launch_bounds__(64)
void ctc_combine(const ushort* __restrict__ Wa, const ushort* __restrict__ Wb,
                 const ushort* __restrict__ W4a, const ushort* __restrict__ W4b,
                 const int* __restrict__ Eb, const int* __restrict__ seqg,
                 double* __restrict__ Lq)
{
    const int b = blockIdx.x, q = blockIdx.y, l = threadIdx.x;
    const bool is63 = (l == 63);
    const int* sq = seqg + b*SS;
    const int r1 = sq[SS-1-2*l], r3 = sq[SS-2-2*l];
    const int ip = (l==0) ? 0 : (SS-2*l);
    const float m1 = (l==0) ? 1.f : ((r1 != sq[ip]) ? 1.f : 0.f);
    const float m3 = (r3 != r1) ? 1.f : 0.f;
    const int tm0=(4*l+769)>>1, tm1=(4*l+770)>>1, tm2=(4*l+771)>>1, tm3=(4*l+772)>>1;

    const ushort* WaB = Wa + (size_t)b*TT*LPADH;
    const ushort* WbB = Wb + (size_t)b*TT*LPADH;
    const ushort* W4aB = W4a + (size_t)b*TT;
    const ushort* W4bB = W4b + (size_t)b*TT;
    const int t0 = q*8;

    float Rcur;
    {
        const ushort* rw = WbB + (size_t)(TT-1-t0)*LPADH;
        uint2 xu = *reinterpret_cast<const uint2*>(rw + 4*l);
        float rnp = (up_lo(xu.x)+up_hi(xu.x))+(up_lo(xu.y)+up_hi(xu.y));
        if (is63) rnp += up_us(W4bB[TT-1-t0]);
        Rcur = full64f(rnp);
    }
    double acc = 0.0;

    #pragma unroll
    for (int k=0; k<8; ++k) {
        const int t = t0 + k;
        const int i = TT-1-t;
        const ushort* arow = WaB + (size_t)t*LPADH;
        uint2 au = *reinterpret_cast<const uint2*>(arow + (252 - 4*l));
        float av0 = up_lo(au.x), av1 = up_hi(au.x);
        float av2 = up_lo(au.y), av3 = up_hi(au.y);
        float a256 = up_us(W4aB[t]);
        float ar4 = shfl_up1_f32(av0);
        if (l == 0) ar4 = a256;

        float u0,u1,u2,u3,u4, rnext = 0.f;
        if (i > 0) {
            const ushort* rw = WbB + (size_t)(i-1)*LPADH;
            uint2 bu = *reinterpret_cast<const uint2*>(rw + 4*l);
            float bv0 = up_lo(bu.x), bv1 = up_hi(bu.x);
            float bv2 = up_lo(bu.y), bv3 = up_hi(bu.y);
            float b4 = up_us(W4bB[i-1]);
            float e3u = shfl_up1_f32(bv3);
            u0 = bv0 + e3u;
            u1 = (bv1 + bv0) + m1*e3u;
            u2 = bv2 + bv1;
            u3 = (bv3 + bv2) + m3*bv1;
            u4 = b4 + bv3;
            if (i >= TT - SS) {
                if (i >= tm0) u0 = 0.f;
                if (i >= tm1) u1 = 0.f;
                if (i >= tm2) u2 = 0.f;
                if (i >= tm3) u3 = 0.f;
            }
            rnext = (bv0+bv1)+(bv2+bv3);
            if (is63) rnext += b4;
        } else {
            u0 = (l==0)?1.f:0.f; u1 = u0; u2=0.f; u3=0.f; u4=0.f;
        }
        float trp = ar4*u0 + av3*u1 + av2*u2 + av1*u3;
        if (is63) trp += av0*u4;
        float sap = (av1 + av2) + (av3 + ar4);
        if (is63) sap += av0;

        float D  = full64f(trp);
        float S  = full64f(sap);
        float Rn = full64f(rnext);
        if (is63) {
            double e = (i > 0 && (i & 7) == 0) ? (double)Eb[b*64 + (i>>3)] : 0.0;
            double dd = fmax((double)D, 1e-300);
            double sr = fmax((double)S * (double)Rcur, 1e-300);
            acc += log(dd) - log(sr) - e*M_LN2;
        }
        Rcur = Rn;
    }
    if (is63) Lq[b*64 + q] = acc;
}

// ---- combine diagnostic clone: x5 reps, laundered pointers, dummy output ----
__global__ __launch_bounds__(64)
void ctc_diagC(const ushort* __restrict__ Wa, const ushort* __restrict__ Wb,
               const ushort* __restrict__ W4a, const ushort* __restrict__ W4b,
               const int* __restrict__ Eb, const int* __restrict__ seqg,
               double* __restrict__ Lqdum)
{
    const int b = blockIdx.x, q = blockIdx.y, l = threadIdx.x;
    const bool is63 = (l == 63);
    const int* sq = seqg + b*SS;
    const int r1 = sq[SS-1-2*l], r3 = sq[SS-2-2*l];
    const int ip = (l==0) ? 0 : (SS-2*l);
    const float m1 = (l==0) ? 1.f : ((r1 != sq[ip]) ? 1.f : 0.f);
    const float m3 = (r3 != r1) ? 1.f : 0.f;
    const int tm0=(4*l+769)>>1, tm1=(4*l+770)>>1, tm2=(4*l+771)>>1, tm3=(4*l+772)>>1;
    const int t0 = q*8;

    double accT = 0.0;
    for (int rep=0; rep<5; ++rep) {
        uint z = 0;
        asm volatile("" : "+v"(z));       // opaque 0: defeats cross-rep CSE/hoist
        const ushort* WaB = Wa + (size_t)b*TT*LPADH + z;
        const ushort* WbB = Wb + (size_t)b*TT*LPADH + z;
        const ushort* W4aB = W4a + (size_t)b*TT + z;
        const ushort* W4bB = W4b + (size_t)b*TT + z;

        float Rcur;
        {
            const ushort* rw = WbB + (size_t)(TT-1-t0)*LPADH;
            uint2 xu = *reinterpret_cast<const uint2*>(rw + 4*l);
            float rnp = (up_lo(xu.x)+up_hi(xu.x))+(up_lo(xu.y)+up_hi(xu.y));
            if (is63) rnp += up_us(W4bB[TT-1-t0]);
            Rcur = full64f(rnp);
        }
        double acc = 0.0;
        #pragma unroll
        for (int k=0; k<8; ++k) {
            const int t = t0 + k;
            const int i = TT-1-t;
            const ushort* arow = WaB + (size_t)t*LPADH;
            uint2 au = *reinterpret_cast<const uint2*>(arow + (252 - 4*l));
            float av0 = up_lo(au.x), av1 = up_hi(au.x);
            float av2 = up_lo(au.y), av3 = up_hi(au.y);
            float a256 = up_us(W4aB[t]);
            float ar4 = shfl_up1_f32(av0);
            if (l == 0) ar4 = a256;

            float u0,u1,u2,u3,u4, rnext = 0.f;
            if (i > 0) {
                const ushort* rw = WbB + (size_t)(i-1)*LPADH;
                uint2 bu = *reinterpret_cast<const uint2*>(rw + 4*l);
                float bv0 = up_lo(bu.x), bv1 = up_hi(bu.x);
                float bv2 = up_lo(bu.y), bv3 = up_hi(bu.y);
                float b4 = up_us(W4bB[i-1]);
                float e3u = shfl_up1_f32(bv3);
                u0 = bv0 + e3u;
                u1 = (bv1 + bv0) + m1*e3u;
                u2 = bv2 + bv1;
                u3 = (bv3 + bv2) + m3*bv1;
                u4 = b4 + bv3;
                if (i >= TT - SS) {
                    if (i >= tm0) u0 = 0.f;
                    if (i >= tm1) u1 = 0.f;
                    if (i >= tm2) u2 = 0.f;
                    if (i >= tm3) u3 = 0.f;
                }
                rnext = (bv0+bv1)+(bv2+bv3);
                if (is63) rnext += b4;
            } else {
                u0 = (l==0)?1.f:0.f; u1 = u0; u2=0.f; u3=0.f; u4=0.f;
            }
            float trp = ar4*u0 + av3*u1 + av2*u2 + av1*u3;
            if (is63) trp += av0*u4;
            float sap = (av1 + av2) + (av3 + ar4);
            if (is63) sap += av0;

            float D  = full64f(trp);
            float S  = full64f(sap);
            float Rn = full64f(rnext);
            if (is63) {
                double e = (i > 0 && (i & 7) == 0) ? (double)Eb[b*64 + (i>>3)] : 0.0;
                double dd = fmax((double)D, 1e-300);
                double sr = fmax((double)S * (double)Rcur, 1e-300);
                acc += log(dd) - log(sr) - e*M_LN2;
            }
            Rcur = Rn;
        }
        accT += acc;
    }
    if (is63) Lqdum[b*64 + q] = accT;
}

__global__ __launch_bounds__(256)
void ctc_final(const double* __restrict__ Lq, float* __restrict__ out)
{
    const int t = threadIdx.x;
    double v = 0.0;
    #pragma unroll
    for (int k=0;k<32;++k) v += Lq[t + 256*k];
    double s = full64d(v);
    __shared__ double w[4];
    if ((t & 63) == 63) w[t>>6] = s;
    __syncthreads();
    if (t == 0) out[0] = (float)(-(w[0]+w[1]+w[2]+w[3]));
}

extern "C" void kernel_launch(void* const* d_in, const int* in_sizes, int n_in,
                              void* d_out, int out_size, void* d_ws, size_t ws_size,
                              hipStream_t stream)
{
    const float* P     = (const float*)d_in[0];   // params (B,C,T) fp32
    const int*   seq   = (const int*)  d_in[1];   // (B,S) int32
    // d_in[2] = lengths (unused by the reference computation)
    const int*   blank = (const int*)  d_in[3];   // scalar int

    // real ws layout (bf16 rows): Wa | Wb (34.1 MB each) | W4a | W4b | Lq | Eb
    ushort* Wa  = (ushort*)d_ws;
    ushort* Wb  = Wa  + (size_t)BB*TT*LPADH;
    ushort* W4a = Wb  + (size_t)BB*TT*LPADH;
    ushort* W4b = W4a + (size_t)BB*TT;
    double* Lq  = (double*)(W4b + (size_t)BB*TT);
    int*    Eb  = (int*)(Lq + (size_t)BB*64);
    // diagnostic dummy region at 256 MiB offset (ws is 512 MiB per harness fill)
    char* dumBase = (char*)d_ws + ((size_t)256 << 20);
    ushort* Wdum  = (ushort*)dumBase;                         // 68.2 MB (256 blk)
    ushort* W4dum = Wdum + (size_t)2*BB*TT*LPADH;             // 256 KB
    double* Lqdum = (double*)(W4dum + (size_t)2*BB*TT);       // 64 KB
    (void)ws_size; (void)in_sizes; (void)n_in; (void)out_size;

    ctc_scan<<<2*BB, 64, 0, stream>>>(P, seq, blank, Wa, Wb, W4a, W4b, Eb);
    ctc_diagL<<<2*BB, 64, 0, stream>>>(P, seq, blank, Wdum, W4dum);
    ctc_diagS<<<2*BB, 64, 0, stream>>>(P, seq, blank, Wdum, W4dum);
    ctc_diagM<<<2*BB, 64, 0, stream>>>(P, seq, blank, Wdum, W4dum);
    ctc_diagC<<<dim3(BB, 64), 64, 0, stream>>>(Wa, Wb, W4a, W4b, Eb, seq, Lqdum);
    ctc_combine<<<dim3(BB, 64), 64, 0, stream>>>(Wa, Wb, W4a, W4b, Eb, seq, Lq);
    ctc_final<<<1, 256, 0, stream>>>(Lq, (float*)d_out);
}

// Round 14
// 82.230 us; speedup vs baseline: 6.1856x; 6.1856x over previous
//
#include <hip/hip_runtime.h>
#include <math.h>

// CTC loss (per-step-normalized fwd/bwd), B=128, C=512, T=512, S=128, L=257.
// Round-14: combine de-VALU-ization (r13 diag: combine ~29us/rep, VALUBusy 93%
// -> VALU-throughput-bound; 2 fp64 logs + 3 wave reductions per iter were the
// cost). Loss separates: -sum log lh = -sum logD + sum logS_t + sum logR_i
// + ln2*sum e_g. So:
//  - scans ALSO store per-step row sums Sa[t], Rb[i] (fp32; per-step full64f
//    fills the scans' idle VALU slots; group-buffered float4 stores, lane 63)
//  - combine computes ONLY D per t: 1 reduction/iter; logs replaced by fp32
//    exponent-add + mantissa-product (8 mantissas in [1,2): no renorm), ONE
//    fp64 log per 8 steps
//  - new ctc_logs kernel: parallel fp64 logs of Sa/Rb + Eb*ln2 term
// Identity (validated r4-r13): lh_t = sigma_i * D/(S_t*R_i), i = T-1-t.
// bf16 rows; fp64 final accumulation; logs clamped -> no NaN possible.

#define BB 128
#define CC 512
#define TT 512
#define SS 128
#define LL 257
#define LPADH 260   // bf16 (ushort) elements per row

typedef unsigned int  uint;
typedef unsigned short ushort;

// ---- fp32 DPP helpers (gfx9 controls; validated on gfx950 rounds 3-13) ----
template<int CTRL>
__device__ __forceinline__ float dpp0_f32(float x){
    int v = __builtin_bit_cast(int, x);
    int r = __builtin_amdgcn_update_dpp(0, v, CTRL, 0xF, 0xF, true);
    return __builtin_bit_cast(float, r);
}
__device__ __forceinline__ float shfl_up1_f32(float x){ return dpp0_f32<0x138>(x); }
__device__ __forceinline__ float red8f(float x){
    x += dpp0_f32<0x111>(x);
    x += dpp0_f32<0x112>(x);
    x += dpp0_f32<0x114>(x);
    return x;
}
__device__ __forceinline__ float tail3f(float x){
    x += dpp0_f32<0x118>(x);
    x += dpp0_f32<0x142>(x);
    x += dpp0_f32<0x143>(x);
    return x;
}
__device__ __forceinline__ float full64f(float x){ return tail3f(red8f(x)); }
__device__ __forceinline__ float readlane63_f32(float x){
    int v = __builtin_bit_cast(int, x);
    return __builtin_bit_cast(float, __builtin_amdgcn_readlane(v, 63));
}
__device__ __forceinline__ float pow2if(int e){
    return __builtin_bit_cast(float, (127 + e) << 23);
}
__device__ __forceinline__ uint pk_bf16(float lo, float hi){
    return (__builtin_bit_cast(uint, hi) & 0xFFFF0000u)
         | (__builtin_bit_cast(uint, lo) >> 16);
}
__device__ __forceinline__ float up_lo(uint u){ return __builtin_bit_cast(float, u << 16); }
__device__ __forceinline__ float up_hi(uint u){ return __builtin_bit_cast(float, u & 0xFFFF0000u); }
__device__ __forceinline__ float up_us(ushort u){ return __builtin_bit_cast(float, ((uint)u) << 16); }
template<int CTRL>
__device__ __forceinline__ double dpp0_f64(double x){
    int2 v = __builtin_bit_cast(int2, x);
    int2 r;
    r.x = __builtin_amdgcn_update_dpp(0, v.x, CTRL, 0xF, 0xF, true);
    r.y = __builtin_amdgcn_update_dpp(0, v.y, CTRL, 0xF, 0xF, true);
    return __builtin_bit_cast(double, r);
}
__device__ __forceinline__ double full64d(double x){
    x += dpp0_f64<0x111>(x); x += dpp0_f64<0x112>(x); x += dpp0_f64<0x114>(x);
    x += dpp0_f64<0x118>(x); x += dpp0_f64<0x142>(x); x += dpp0_f64<0x143>(x);
    return x;
}

// =================== row-storing scan (both roles, bf16 rows + row sums) ===================
template<bool REV>
__device__ __forceinline__ void scan_body(
    int b, int l, const float* __restrict__ P, const int* __restrict__ seqg,
    int blank, ushort* __restrict__ W, ushort* __restrict__ W4,
    float* __restrict__ SR, int* __restrict__ Eb)
{
    const bool is63 = (l == 63);
    const float* Pb = P + (size_t)b * (CC*TT);
    const int* sq = seqg + b*SS;

    int r1, r3; float m1, m3;
    if (!REV) {
        r1 = sq[2*l]; r3 = sq[2*l+1];
        int ip = (l==0) ? 0 : (2*l-1);
        m1 = (l==0) ? 1.f : ((r1 != sq[ip]) ? 1.f : 0.f);
        m3 = (r3 != r1) ? 1.f : 0.f;
    } else {
        r1 = sq[SS-1-2*l]; r3 = sq[SS-2-2*l];
        int ip = (l==0) ? 0 : (SS-2*l);
        m1 = (l==0) ? 1.f : ((r1 != sq[ip]) ? 1.f : 0.f);
        m3 = (r3 != r1) ? 1.f : 0.f;
    }
    const float* pBp = Pb + (size_t)blank*TT;
    const float* p1p = Pb + (size_t)r1*TT;
    const float* p3p = Pb + (size_t)r3*TT;
    ushort* Ww  = W  + (size_t)b*TT*LPADH;
    ushort* W4b = W4 + (size_t)b*TT;
    float* SRb  = SR + (size_t)b*TT;
    int* EbB = Eb + b*64;

    const int tm0=(4*l+769)>>1, tm1=(4*l+770)>>1, tm2=(4*l+771)>>1, tm3=(4*l+772)>>1;

    float pbB[8], pb1[8], pb3[8];
    #pragma unroll
    for (int j=0;j<8;++j){
        int pc = REV ? (TT-1-j) : j;
        pbB[j]=pBp[pc]; pb1[j]=p1p[pc]; pb3[j]=p3p[pc];
    }

    float a0=0.f,a1=0.f,a2=0.f,a3=0.f,a4=0.f;
    float scNext = 1.f, Sfull = 0.f;
    const float u0i = (l==0) ? 1.f : 0.f;
    uint sbLo[8], sbHi[8]; float s4f[8]; float ssum[8];

#define STEP(i, j, FIRSTF, MASKF)                                           \
  {                                                                         \
    float u0,u1,u2,u3,u4;                                                   \
    if (FIRSTF) { u0=u0i; u1=u0i; u2=0.f; u3=0.f; u4=0.f; }                 \
    else {                                                                  \
      float e3u = shfl_up1_f32(a3);                                         \
      u0 = a0 + e3u; u1 = (a1+a0) + m1*e3u; u2 = a2+a1;                     \
      u3 = (a3+a2) + m3*a1; u4 = a4+a3;                                     \
      if (MASKF) {                                                          \
        if ((i) >= tm0) u0 = 0.f;                                           \
        if ((i) >= tm1) u1 = 0.f;                                           \
        if ((i) >= tm2) u2 = 0.f;                                           \
        if ((i) >= tm3) u3 = 0.f;                                           \
      }                                                                     \
    }                                                                       \
    float pB=pbB[j], pq=pb1[j], pr=pb3[j];                                  \
    if ((j)==0) { pB*=scNext; pq*=scNext; pr*=scNext; }                     \
    float n0=u0*pB, n1=u1*pq, n2=u2*pB, n3=u3*pr, n4=u4*pB;                 \
    sbLo[j]=pk_bf16(n0,n1); sbHi[j]=pk_bf16(n2,n3); s4f[j]=n4;              \
    {                                                                       \
      float part=(n0+n1)+(n2+n3); if (is63) part+=n4;                       \
      float Sf = full64f(part);                                             \
      ssum[j] = Sf;                                                         \
      if ((j)==5) Sfull = Sf;                                               \
    }                                                                       \
    if ((j)==7) {                                                           \
      float Su = readlane63_f32(Sfull);                                     \
      int ex = (__builtin_bit_cast(int, Su) >> 23) & 0xFF;                  \
      int e = (ex==0) ? 0 : (ex-127);                                       \
      e = e < -120 ? -120 : (e > 120 ? 120 : e);                            \
      scNext = pow2if(-e);                                                  \
      if (REV && l==0 && (i)+1 < TT) EbB[((i)+1)>>3] = e;                   \
    }                                                                       \
    a0=n0; a1=n1; a2=n2; a3=n3; a4=n4;                                      \
    int inx = ((i)+8 < TT) ? (i)+8 : TT-1;                                  \
    int pcn = REV ? (TT-1-inx) : inx;                                       \
    pbB[j]=pBp[pcn]; pb1[j]=p1p[pcn]; pb3[j]=p3p[pcn];                      \
  }

#define GSTORE(i0)                                                          \
  {                                                                         \
    _Pragma("unroll")                                                       \
    for (int j=0;j<8;++j)                                                   \
      *reinterpret_cast<uint2*>(Ww + (size_t)j*LPADH + 4*l)                 \
          = make_uint2(sbLo[j], sbHi[j]);                                   \
    if (is63) {                                                             \
      uint4 pk;                                                             \
      pk.x = pk_bf16(s4f[0], s4f[1]);                                       \
      pk.y = pk_bf16(s4f[2], s4f[3]);                                       \
      pk.z = pk_bf16(s4f[4], s4f[5]);                                       \
      pk.w = pk_bf16(s4f[6], s4f[7]);                                       \
      *reinterpret_cast<uint4*>(W4b + (i0)) = pk;                           \
      *reinterpret_cast<float4*>(SRb + (i0))                                \
          = make_float4(ssum[0], ssum[1], ssum[2], ssum[3]);                \
      *reinterpret_cast<float4*>(SRb + (i0) + 4)                            \
          = make_float4(ssum[4], ssum[5], ssum[6], ssum[7]);                \
    }                                                                       \
    Ww += 8*LPADH;                                                          \
  }

    STEP(0,0,true,false)  STEP(1,1,false,false) STEP(2,2,false,false)
    STEP(3,3,false,false) STEP(4,4,false,false) STEP(5,5,false,false)
    STEP(6,6,false,false) STEP(7,7,false,false)
    GSTORE(0)
    for (int i0=8; i0<TT-SS; i0+=8) {
        #pragma unroll
        for (int j=0;j<8;++j) STEP(i0+j, j, false, false)
        GSTORE(i0)
    }
    for (int i0=TT-SS; i0<TT; i0+=8) {
        #pragma unroll
        for (int j=0;j<8;++j) STEP(i0+j, j, false, true)
        GSTORE(i0)
    }
#undef STEP
#undef GSTORE
}

__global__ __launch_bounds__(64, 1)
void ctc_scan(const float* __restrict__ P, const int* __restrict__ seqg,
              const int* __restrict__ blankp, ushort* __restrict__ Wa,
              ushort* __restrict__ Wb, ushort* __restrict__ W4a,
              ushort* __restrict__ W4b, float* __restrict__ Sa,
              float* __restrict__ Rb, int* __restrict__ Eb)
{
    const int bx = blockIdx.x, l = threadIdx.x;
    const int blank = blankp[0];
    if (bx < BB) scan_body<false>(bx,      l, P, seqg, blank, Wa, W4a, Sa, Eb);
    else         scan_body<true >(bx - BB, l, P, seqg, blank, Wb, W4b, Rb, Eb);
}

// ================= combine: D only; exponent+mantissa accumulation =================
// Block (b, q): one wave handles t = 8q .. 8q+7.  i = T-1-t.
// Writes LqD[b][q] = sum_t log D_t  (one fp64 log per 8 steps).
__global__ __launch_bounds__(64)
void ctc_combine(const ushort* __restrict__ Wa, const ushort* __restrict__ Wb,
                 const ushort* __restrict__ W4a, const ushort* __restrict__ W4b,
                 const int* __restrict__ seqg, double* __restrict__ LqD)
{
    const int b = blockIdx.x, q = blockIdx.y, l = threadIdx.x;
    const bool is63 = (l == 63);
    const int* sq = seqg + b*SS;
    const int r1 = sq[SS-1-2*l], r3 = sq[SS-2-2*l];
    const int ip = (l==0) ? 0 : (SS-2*l);
    const float m1 = (l==0) ? 1.f : ((r1 != sq[ip]) ? 1.f : 0.f);
    const float m3 = (r3 != r1) ? 1.f : 0.f;
    const int tm0=(4*l+769)>>1, tm1=(4*l+770)>>1, tm2=(4*l+771)>>1, tm3=(4*l+772)>>1;

    const ushort* WaB = Wa + (size_t)b*TT*LPADH;
    const ushort* WbB = Wb + (size_t)b*TT*LPADH;
    const ushort* W4aB = W4a + (size_t)b*TT;
    const ushort* W4bB = W4b + (size_t)b*TT;
    const int t0 = q*8;

    float Pm = 1.f;     // mantissa product, in [1, 256) after 8 iters
    int   Ed = 0;       // unbiased exponent sum

    #pragma unroll
    for (int k=0; k<8; ++k) {
        const int t = t0 + k;
        const int i = TT-1-t;
        const ushort* arow = WaB + (size_t)t*LPADH;
        uint2 au = *reinterpret_cast<const uint2*>(arow + (252 - 4*l));
        float av0 = up_lo(au.x), av1 = up_hi(au.x);
        float av2 = up_lo(au.y), av3 = up_hi(au.y);
        float a256 = up_us(W4aB[t]);
        float ar4 = shfl_up1_f32(av0);
        if (l == 0) ar4 = a256;

        float u0,u1,u2,u3,u4;
        if (i > 0) {
            const ushort* rw = WbB + (size_t)(i-1)*LPADH;
            uint2 bu = *reinterpret_cast<const uint2*>(rw + 4*l);
            float bv0 = up_lo(bu.x), bv1 = up_hi(bu.x);
            float bv2 = up_lo(bu.y), bv3 = up_hi(bu.y);
            float b4 = up_us(W4bB[i-1]);
            float e3u = shfl_up1_f32(bv3);
            u0 = bv0 + e3u;
            u1 = (bv1 + bv0) + m1*e3u;
            u2 = bv2 + bv1;
            u3 = (bv3 + bv2) + m3*bv1;
            u4 = b4 + bv3;
            if (i >= TT - SS) {
                if (i >= tm0) u0 = 0.f;
                if (i >= tm1) u1 = 0.f;
                if (i >= tm2) u2 = 0.f;
                if (i >= tm3) u3 = 0.f;
            }
        } else {
            u0 = (l==0)?1.f:0.f; u1 = u0; u2=0.f; u3=0.f; u4=0.f;
        }
        float trp = ar4*u0 + av3*u1 + av2*u2 + av1*u3;
        if (is63) trp += av0*u4;

        float D = full64f(trp);               // valid on lane 63
        if (is63) {
            float dd = fmaxf(D, 1e-37f);
            uint bits = __builtin_bit_cast(uint, dd);
            Ed += (int)((bits >> 23) & 0xFFu) - 127;
            float m = __builtin_bit_cast(float, (bits & 0x807FFFFFu) | (127u<<23));
            Pm *= m;                          // in [1,2) each; no renorm needed
        }
    }
    if (is63) LqD[b*64 + q] = log((double)Pm) + (double)Ed * M_LN2;
}

// ============ parallel logs of the row sums (+ Eb term) -> LqS[b] ============
// LqS[b] = sum_t log Sa + sum_i log Rb + ln2 * sum_{g>=1} e_g
__global__ __launch_bounds__(64)
void ctc_logs(const float* __restrict__ Sa, const float* __restrict__ Rb,
              const int* __restrict__ Eb, double* __restrict__ LqS)
{
    const int b = blockIdx.x, l = threadIdx.x;
    double s = 0.0;
    #pragma unroll
    for (int k=0;k<8;++k) {
        int t = k*64 + l;
        double sv = fmax((double)Sa[(size_t)b*TT + t], 1e-300);
        double rv = fmax((double)Rb[(size_t)b*TT + t], 1e-300);
        s += log(sv) + log(rv);
    }
    if (l > 0) s += M_LN2 * (double)Eb[b*64 + l];   // groups g = 1..63
    double tot = full64d(s);
    if (l == 63) LqS[b] = tot;
}

__global__ __launch_bounds__(256)
void ctc_final(const double* __restrict__ LqD, const double* __restrict__ LqS,
               float* __restrict__ out)
{
    const int t = threadIdx.x;
    // loss = sum_b [ LqS[b] - sum_q LqD[b][q] ]
    double v = 0.0;
    #pragma unroll
    for (int k=0;k<32;++k) v -= LqD[t + 256*k];
    if (t < BB) v += LqS[t];
    double s = full64d(v);
    __shared__ double w[4];
    if ((t & 63) == 63) w[t>>6] = s;
    __syncthreads();
    if (t == 0) out[0] = (float)(w[0]+w[1]+w[2]+w[3]);
}

extern "C" void kernel_launch(void* const* d_in, const int* in_sizes, int n_in,
                              void* d_out, int out_size, void* d_ws, size_t ws_size,
                              hipStream_t stream)
{
    const float* P     = (const float*)d_in[0];   // params (B,C,T) fp32
    const int*   seq   = (const int*)  d_in[1];   // (B,S) int32
    // d_in[2] = lengths (unused by the reference computation)
    const int*   blank = (const int*)  d_in[3];   // scalar int

    // ws layout: Wa | Wb (34.1 MB each) | W4a | W4b | LqD | Eb | Sa | Rb | LqS
    ushort* Wa  = (ushort*)d_ws;
    ushort* Wb  = Wa  + (size_t)BB*TT*LPADH;
    ushort* W4a = Wb  + (size_t)BB*TT*LPADH;
    ushort* W4b = W4a + (size_t)BB*TT;
    double* LqD = (double*)(W4b + (size_t)BB*TT);       // 8192 doubles
    int*    Eb  = (int*)(LqD + (size_t)BB*64);          // 8192 ints
    float*  Sa  = (float*)(Eb + (size_t)BB*64);         // BB*TT floats
    float*  Rb  = Sa + (size_t)BB*TT;                   // BB*TT floats
    double* LqS = (double*)(Rb + (size_t)BB*TT);        // 128 doubles
    (void)ws_size; (void)in_sizes; (void)n_in; (void)out_size;

    ctc_scan<<<2*BB, 64, 0, stream>>>(P, seq, blank, Wa, Wb, W4a, W4b, Sa, Rb, Eb);
    ctc_combine<<<dim3(BB, 64), 64, 0, stream>>>(Wa, Wb, W4a, W4b, seq, LqD);
    ctc_logs<<<BB, 64, 0, stream>>>(Sa, Rb, Eb, LqS);
    ctc_final<<<1, 256, 0, stream>>>(LqD, LqS, (float*)d_out);
}

// Round 15
// 64.820 us; speedup vs baseline: 7.8471x; 1.2686x over previous
//
#include <hip/hip_runtime.h>
#include <math.h>

// CTC loss (per-step-normalized fwd/bwd), B=128, C=512, T=512, S=128, L=257.
// Round-15: r10 scan (best passing build, 79.5us) + r9 combine structure with
// r14's exponent/mantissa log elimination (r13 diag: combine 29us/rep at 93%
// VALUBusy -> VALU-bound; the two per-iter fp64 logs were the largest term).
// Per iter now: integer exponent accumulate + fp32 mantissa product for BOTH
// numerator D and denominator S*R (+ Eb term folded into the same integer);
// ONE fp64 log per 8 iters. r14 lesson applied: add work to full-occupancy
// kernels (cost ~ issue), never to the 1-wave latency-bound scan (cost ~ 3x).
// Identity (r4-r13): lh_t = sigma_i * D/(S_t*R_i), i = T-1-t.
// bf16 rows; fp64 block accumulation; clamps -> no NaN possible.

#define BB 128
#define CC 512
#define TT 512
#define SS 128
#define LL 257
#define LPADH 260   // bf16 (ushort) elements per row

typedef unsigned int  uint;
typedef unsigned short ushort;

// ---- fp32 DPP helpers (gfx9 controls; validated on gfx950 rounds 3-14) ----
template<int CTRL>
__device__ __forceinline__ float dpp0_f32(float x){
    int v = __builtin_bit_cast(int, x);
    int r = __builtin_amdgcn_update_dpp(0, v, CTRL, 0xF, 0xF, true);
    return __builtin_bit_cast(float, r);
}
__device__ __forceinline__ float shfl_up1_f32(float x){ return dpp0_f32<0x138>(x); }
__device__ __forceinline__ float red8f(float x){
    x += dpp0_f32<0x111>(x);
    x += dpp0_f32<0x112>(x);
    x += dpp0_f32<0x114>(x);
    return x;
}
__device__ __forceinline__ float tail3f(float x){
    x += dpp0_f32<0x118>(x);
    x += dpp0_f32<0x142>(x);
    x += dpp0_f32<0x143>(x);
    return x;
}
__device__ __forceinline__ float full64f(float x){ return tail3f(red8f(x)); }
__device__ __forceinline__ float readlane63_f32(float x){
    int v = __builtin_bit_cast(int, x);
    return __builtin_bit_cast(float, __builtin_amdgcn_readlane(v, 63));
}
__device__ __forceinline__ float pow2if(int e){
    return __builtin_bit_cast(float, (127 + e) << 23);
}
__device__ __forceinline__ uint pk_bf16(float lo, float hi){
    return (__builtin_bit_cast(uint, hi) & 0xFFFF0000u)
         | (__builtin_bit_cast(uint, lo) >> 16);
}
__device__ __forceinline__ float up_lo(uint u){ return __builtin_bit_cast(float, u << 16); }
__device__ __forceinline__ float up_hi(uint u){ return __builtin_bit_cast(float, u & 0xFFFF0000u); }
__device__ __forceinline__ float up_us(ushort u){ return __builtin_bit_cast(float, ((uint)u) << 16); }
template<int CTRL>
__device__ __forceinline__ double dpp0_f64(double x){
    int2 v = __builtin_bit_cast(int2, x);
    int2 r;
    r.x = __builtin_amdgcn_update_dpp(0, v.x, CTRL, 0xF, 0xF, true);
    r.y = __builtin_amdgcn_update_dpp(0, v.y, CTRL, 0xF, 0xF, true);
    return __builtin_bit_cast(double, r);
}
__device__ __forceinline__ double full64d(double x){
    x += dpp0_f64<0x111>(x); x += dpp0_f64<0x112>(x); x += dpp0_f64<0x114>(x);
    x += dpp0_f64<0x118>(x); x += dpp0_f64<0x142>(x); x += dpp0_f64<0x143>(x);
    return x;
}

// =================== row-storing scan (r10 verbatim) ===================
template<bool REV>
__device__ __forceinline__ void scan_body(
    int b, int l, const float* __restrict__ P, const int* __restrict__ seqg,
    int blank, ushort* __restrict__ W, ushort* __restrict__ W4,
    int* __restrict__ Eb)
{
    const bool is63 = (l == 63);
    const float* Pb = P + (size_t)b * (CC*TT);
    const int* sq = seqg + b*SS;

    int r1, r3; float m1, m3;
    if (!REV) {
        r1 = sq[2*l]; r3 = sq[2*l+1];
        int ip = (l==0) ? 0 : (2*l-1);
        m1 = (l==0) ? 1.f : ((r1 != sq[ip]) ? 1.f : 0.f);
        m3 = (r3 != r1) ? 1.f : 0.f;
    } else {
        r1 = sq[SS-1-2*l]; r3 = sq[SS-2-2*l];
        int ip = (l==0) ? 0 : (SS-2*l);
        m1 = (l==0) ? 1.f : ((r1 != sq[ip]) ? 1.f : 0.f);
        m3 = (r3 != r1) ? 1.f : 0.f;
    }
    const float* pBp = Pb + (size_t)blank*TT;
    const float* p1p = Pb + (size_t)r1*TT;
    const float* p3p = Pb + (size_t)r3*TT;
    ushort* Ww  = W  + (size_t)b*TT*LPADH;
    ushort* W4b = W4 + (size_t)b*TT;
    int* EbB = Eb + b*64;

    const int tm0=(4*l+769)>>1, tm1=(4*l+770)>>1, tm2=(4*l+771)>>1, tm3=(4*l+772)>>1;

    float pbB[8], pb1[8], pb3[8];
    #pragma unroll
    for (int j=0;j<8;++j){
        int pc = REV ? (TT-1-j) : j;
        pbB[j]=pBp[pc]; pb1[j]=p1p[pc]; pb3[j]=p3p[pc];
    }

    float a0=0.f,a1=0.f,a2=0.f,a3=0.f,a4=0.f;
    float scNext = 1.f, Sfull = 0.f;
    const float u0i = (l==0) ? 1.f : 0.f;
    uint sbLo[8], sbHi[8]; float s4f[8];

#define STEP(i, j, FIRSTF, MASKF)                                           \
  {                                                                         \
    float u0,u1,u2,u3,u4;                                                   \
    if (FIRSTF) { u0=u0i; u1=u0i; u2=0.f; u3=0.f; u4=0.f; }                 \
    else {                                                                  \
      float e3u = shfl_up1_f32(a3);                                         \
      u0 = a0 + e3u; u1 = (a1+a0) + m1*e3u; u2 = a2+a1;                     \
      u3 = (a3+a2) + m3*a1; u4 = a4+a3;                                     \
      if (MASKF) {                                                          \
        if ((i) >= tm0) u0 = 0.f;                                           \
        if ((i) >= tm1) u1 = 0.f;                                           \
        if ((i) >= tm2) u2 = 0.f;                                           \
        if ((i) >= tm3) u3 = 0.f;                                           \
      }                                                                     \
    }                                                                       \
    float pB=pbB[j], pq=pb1[j], pr=pb3[j];                                  \
    if ((j)==0) { pB*=scNext; pq*=scNext; pr*=scNext; }                     \
    float n0=u0*pB, n1=u1*pq, n2=u2*pB, n3=u3*pr, n4=u4*pB;                 \
    sbLo[j]=pk_bf16(n0,n1); sbHi[j]=pk_bf16(n2,n3); s4f[j]=n4;              \
    if ((j)==5) {                                                           \
      float part=(n0+n1)+(n2+n3); if (is63) part+=n4;                       \
      Sfull = full64f(part);                                                \
    }                                                                       \
    if ((j)==7) {                                                           \
      float Su = readlane63_f32(Sfull);                                     \
      int ex = (__builtin_bit_cast(int, Su) >> 23) & 0xFF;                  \
      int e = (ex==0) ? 0 : (ex-127);                                       \
      e = e < -120 ? -120 : (e > 120 ? 120 : e);                            \
      scNext = pow2if(-e);                                                  \
      if (REV && l==0 && (i)+1 < TT) EbB[((i)+1)>>3] = e;                   \
    }                                                                       \
    a0=n0; a1=n1; a2=n2; a3=n3; a4=n4;                                      \
    int inx = ((i)+8 < TT) ? (i)+8 : TT-1;                                  \
    int pcn = REV ? (TT-1-inx) : inx;                                       \
    pbB[j]=pBp[pcn]; pb1[j]=p1p[pcn]; pb3[j]=p3p[pcn];                      \
  }

#define GSTORE(i0)                                                          \
  {                                                                         \
    _Pragma("unroll")                                                       \
    for (int j=0;j<8;++j)                                                   \
      *reinterpret_cast<uint2*>(Ww + (size_t)j*LPADH + 4*l)                 \
          = make_uint2(sbLo[j], sbHi[j]);                                   \
    if (is63) {                                                             \
      uint4 pk;                                                             \
      pk.x = pk_bf16(s4f[0], s4f[1]);                                       \
      pk.y = pk_bf16(s4f[2], s4f[3]);                                       \
      pk.z = pk_bf16(s4f[4], s4f[5]);                                       \
      pk.w = pk_bf16(s4f[6], s4f[7]);                                       \
      *reinterpret_cast<uint4*>(W4b + (i0)) = pk;                           \
    }                                                                       \
    Ww += 8*LPADH;                                                          \
  }

    STEP(0,0,true,false)  STEP(1,1,false,false) STEP(2,2,false,false)
    STEP(3,3,false,false) STEP(4,4,false,false) STEP(5,5,false,false)
    STEP(6,6,false,false) STEP(7,7,false,false)
    GSTORE(0)
    for (int i0=8; i0<TT-SS; i0+=8) {
        #pragma unroll
        for (int j=0;j<8;++j) STEP(i0+j, j, false, false)
        GSTORE(i0)
    }
    for (int i0=TT-SS; i0<TT; i0+=8) {
        #pragma unroll
        for (int j=0;j<8;++j) STEP(i0+j, j, false, true)
        GSTORE(i0)
    }
#undef STEP
#undef GSTORE
}

__global__ __launch_bounds__(64, 1)
void ctc_scan(const float* __restrict__ P, const int* __restrict__ seqg,
              const int* __restrict__ blankp, ushort* __restrict__ Wa,
              ushort* __restrict__ Wb, ushort* __restrict__ W4a,
              ushort* __restrict__ W4b, int* __restrict__ Eb)
{
    const int bx = blockIdx.x, l = threadIdx.x;
    const int blank = blankp[0];
    if (bx < BB) scan_body<false>(bx,      l, P, seqg, blank, Wa, W4a, Eb);
    else         scan_body<true >(bx - BB, l, P, seqg, blank, Wb, W4b, Eb);
}

// ============== combine: D,S,R per iter; exponent/mantissa logs ==============
// Block (b, q): one wave handles t = 8q .. 8q+7.  i = T-1-t.
// Lq[b][q] = sum_t [log D - log(S_t R_i) - e_g ln2]  with ONE fp64 log/block.
__global__ __launch_bounds__(64)
void ctc_combine(const ushort* __restrict__ Wa, const ushort* __restrict__ Wb,
                 const ushort* __restrict__ W4a, const ushort* __restrict__ W4b,
                 const int* __restrict__ Eb, const int* __restrict__ seqg,
                 double* __restrict__ Lq)
{
    const int b = blockIdx.x, q = blockIdx.y, l = threadIdx.x;
    const bool is63 = (l == 63);
    const int* sq = seqg + b*SS;
    const int r1 = sq[SS-1-2*l], r3 = sq[SS-2-2*l];
    const int ip = (l==0) ? 0 : (SS-2*l);
    const float m1 = (l==0) ? 1.f : ((r1 != sq[ip]) ? 1.f : 0.f);
    const float m3 = (r3 != r1) ? 1.f : 0.f;
    const int tm0=(4*l+769)>>1, tm1=(4*l+770)>>1, tm2=(4*l+771)>>1, tm3=(4*l+772)>>1;

    const ushort* WaB = Wa + (size_t)b*TT*LPADH;
    const ushort* WbB = Wb + (size_t)b*TT*LPADH;
    const ushort* W4aB = W4a + (size_t)b*TT;
    const ushort* W4bB = W4b + (size_t)b*TT;
    const int t0 = q*8;

    float Rcur;
    {
        const ushort* rw = WbB + (size_t)(TT-1-t0)*LPADH;
        uint2 xu = *reinterpret_cast<const uint2*>(rw + 4*l);
        float rnp = (up_lo(xu.x)+up_hi(xu.x))+(up_lo(xu.y)+up_hi(xu.y));
        if (is63) rnp += up_us(W4bB[TT-1-t0]);
        Rcur = full64f(rnp);          // valid on lane 63 (consumed there)
    }

    float PmN = 1.f, PmD = 1.f;   // mantissa products: [1,2^8), [1,2^16)
    int   Ei  = 0;                // exponent sum: edN - edD - e_g terms

    #pragma unroll
    for (int k=0; k<8; ++k) {
        const int t = t0 + k;
        const int i = TT-1-t;
        const ushort* arow = WaB + (size_t)t*LPADH;
        uint2 au = *reinterpret_cast<const uint2*>(arow + (252 - 4*l));
        float av0 = up_lo(au.x), av1 = up_hi(au.x);
        float av2 = up_lo(au.y), av3 = up_hi(au.y);
        float a256 = up_us(W4aB[t]);
        float ar4 = shfl_up1_f32(av0);
        if (l == 0) ar4 = a256;

        float u0,u1,u2,u3,u4, rnext = 0.f;
        if (i > 0) {
            const ushort* rw = WbB + (size_t)(i-1)*LPADH;
            uint2 bu = *reinterpret_cast<const uint2*>(rw + 4*l);
            float bv0 = up_lo(bu.x), bv1 = up_hi(bu.x);
            float bv2 = up_lo(bu.y), bv3 = up_hi(bu.y);
            float b4 = up_us(W4bB[i-1]);
            float e3u = shfl_up1_f32(bv3);
            u0 = bv0 + e3u;
            u1 = (bv1 + bv0) + m1*e3u;
            u2 = bv2 + bv1;
            u3 = (bv3 + bv2) + m3*bv1;
            u4 = b4 + bv3;
            if (i >= TT - SS) {
                if (i >= tm0) u0 = 0.f;
                if (i >= tm1) u1 = 0.f;
                if (i >= tm2) u2 = 0.f;
                if (i >= tm3) u3 = 0.f;
            }
            rnext = (bv0+bv1)+(bv2+bv3);
            if (is63) rnext += b4;
        } else {
            u0 = (l==0)?1.f:0.f; u1 = u0; u2=0.f; u3=0.f; u4=0.f;
        }
        float trp = ar4*u0 + av3*u1 + av2*u2 + av1*u3;
        if (is63) trp += av0*u4;
        float sap = (av1 + av2) + (av3 + ar4);
        if (is63) sap += av0;

        float D  = full64f(trp);
        float S  = full64f(sap);
        float Rn = full64f(rnext);
        if (is63) {
            float dd = fmaxf(D, 1e-37f);
            uint bn = __builtin_bit_cast(uint, dd);
            Ei += (int)((bn >> 23) & 0xFFu) - 127;
            PmN *= __builtin_bit_cast(float, (bn & 0x807FFFFFu) | (127u<<23));
            float sr = fmaxf(S * Rcur, 1e-37f);
            uint bd = __builtin_bit_cast(uint, sr);
            Ei -= (int)((bd >> 23) & 0xFFu) - 127;
            PmD *= __builtin_bit_cast(float, (bd & 0x807FFFFFu) | (127u<<23));
            if (i > 0 && (i & 7) == 0) Ei -= Eb[b*64 + (i>>3)];
        }
        Rcur = Rn;
    }
    if (is63)
        Lq[b*64 + q] = log((double)PmN / (double)PmD) + (double)Ei * M_LN2;
}

__global__ __launch_bounds__(256)
void ctc_final(const double* __restrict__ Lq, float* __restrict__ out)
{
    const int t = threadIdx.x;
    double v = 0.0;
    #pragma unroll
    for (int k=0;k<32;++k) v += Lq[t + 256*k];
    double s = full64d(v);
    __shared__ double w[4];
    if ((t & 63) == 63) w[t>>6] = s;
    __syncthreads();
    if (t == 0) out[0] = (float)(-(w[0]+w[1]+w[2]+w[3]));
}

extern "C" void kernel_launch(void* const* d_in, const int* in_sizes, int n_in,
                              void* d_out, int out_size, void* d_ws, size_t ws_size,
                              hipStream_t stream)
{
    const float* P     = (const float*)d_in[0];   // params (B,C,T) fp32
    const int*   seq   = (const int*)  d_in[1];   // (B,S) int32
    // d_in[2] = lengths (unused by the reference computation)
    const int*   blank = (const int*)  d_in[3];   // scalar int

    // ws layout (bf16 rows): Wa | Wb (34.1 MB each) | W4a | W4b | Lq | Eb
    ushort* Wa  = (ushort*)d_ws;
    ushort* Wb  = Wa  + (size_t)BB*TT*LPADH;
    ushort* W4a = Wb  + (size_t)BB*TT*LPADH;      // BB*TT ushorts (128 KB)
    ushort* W4b = W4a + (size_t)BB*TT;
    double* Lq  = (double*)(W4b + (size_t)BB*TT); // 8192 doubles
    int*    Eb  = (int*)(Lq + (size_t)BB*64);     // 8192 ints
    (void)ws_size; (void)in_sizes; (void)n_in; (void)out_size;

    ctc_scan<<<2*BB, 64, 0, stream>>>(P, seq, blank, Wa, Wb, W4a, W4b, Eb);
    ctc_combine<<<dim3(BB, 64), 64, 0, stream>>>(Wa, Wb, W4a, W4b, Eb, seq, Lq);
    ctc_final<<<1, 256, 0, stream>>>(Lq, (float*)d_out);
}